// Round 6
// baseline (175.295 us; speedup 1.0000x reference)
//
#include <hip/hip_runtime.h>
#include <hip/hip_bf16.h>

// Problem constants
#define BATCH 2
#define SEQ   2048
#define CDIM  768
#define HEADS 12
#define DHEAD 64
#define QKV_N 2304   // 3*CDIM
#define ROWS  4096   // BATCH*SEQ

typedef unsigned short u16;
typedef unsigned int   u32;
typedef __attribute__((ext_vector_type(4))) float f32x4;
typedef __attribute__((ext_vector_type(8))) short bf16x8;
typedef __attribute__((ext_vector_type(2))) unsigned int u32x2;

// fp32 -> bf16 (RNE) bit pattern
__device__ __forceinline__ u16 f2b(float f) {
    union { float f; unsigned u; } v; v.f = f;
    unsigned r = v.u + 0x7FFF + ((v.u >> 16) & 1u);
    return (u16)(r >> 16);
}
// bf16 bits -> fp32
__device__ __forceinline__ float b2f(u16 u) {
    union { unsigned i; float f; } x;
    x.i = ((unsigned)u) << 16;
    return x.f;
}
// pack two fp32 -> one u32 of 2x bf16 (RNE), single VALU instruction.
__device__ __forceinline__ u32 cvt_pk_bf16(float lo, float hi) {
    u32 r;
    asm("v_cvt_pk_bf16_f32 %0, %1, %2" : "=v"(r) : "v"(lo), "v"(hi));
    return r;
}

// exp2: native v_exp_f32 when builtin available
#if __has_builtin(__builtin_amdgcn_exp2f)
#define EXP2(x) __builtin_amdgcn_exp2f(x)
#else
#define EXP2(x) __expf((x) * 0.69314718056f)
#endif

// async global->LDS 16B copy
__device__ __forceinline__ void load_lds16(const void* g, void* l) {
    __builtin_amdgcn_global_load_lds(
        (const __attribute__((address_space(1))) u32*)g,
        (__attribute__((address_space(3))) u32*)l, 16, 0, 0);
}

// ---------------------------------------------------------------------------
// Fused prep: x->bf16 (blocks [0,3072)), qkv_w transpose-convert
// (blocks [3072,4800)), proj_w transpose-convert (blocks [4800,5376)).
// ---------------------------------------------------------------------------
#define PREP_CONV 3072          // 4096*768/4 float4 / 256
#define PREP_TQ   1728          // (2304/32) x (768/32)
#define PREP_TP   576           // (768/32) x (768/32)

__device__ __forceinline__ void tconv_body(
    const float* __restrict__ in, u16* __restrict__ out, int R, int C,
    int bi, int bj)
{
    __shared__ float t[32][33];
    const int c = threadIdx.x & 31, r0 = threadIdx.x >> 5;
    #pragma unroll
    for (int i = 0; i < 4; i++) {
        const int r = r0 + i * 8;
        t[r][c] = in[(size_t)(bi * 32 + r) * C + bj * 32 + c];
    }
    __syncthreads();
    #pragma unroll
    for (int i = 0; i < 4; i++) {
        const int r = r0 + i * 8;
        out[(size_t)(bj * 32 + r) * R + bi * 32 + c] = f2b(t[c][r]);
    }
}

__global__ __launch_bounds__(256) void prep_kernel(
    const float* __restrict__ x, u16* __restrict__ xb,
    const float* __restrict__ qkv_w, u16* __restrict__ wT,
    const float* __restrict__ proj_w, u16* __restrict__ pwT)
{
    const int bid = blockIdx.x;
    if (bid < PREP_CONV) {
        const int i = bid * 256 + threadIdx.x;
        const float4 v = reinterpret_cast<const float4*>(x)[i];
        ushort4 o;
        o.x = f2b(v.x); o.y = f2b(v.y); o.z = f2b(v.z); o.w = f2b(v.w);
        reinterpret_cast<ushort4*>(xb)[i] = o;
    } else if (bid < PREP_CONV + PREP_TQ) {
        const int t = bid - PREP_CONV;
        tconv_body(qkv_w, wT, CDIM, QKV_N, t / 72, t % 72);
    } else {
        const int t = bid - PREP_CONV - PREP_TQ;
        tconv_body(proj_w, pwT, CDIM, CDIM, t / 24, t % 24);
    }
}

// ---------------------------------------------------------------------------
// bf16 MFMA GEMM 128x128 BK32, DOUBLE-BUFFERED LDS (1 barrier/K-step),
// + FUSED RMSNorm + RoPE epilogue. q pre-scaled by Dh^-0.5 * log2(e).
// 1-D grid (576 blocks) with XCD-aware swizzle: 576%8==0, bijective remap.
// V6: RoPE-PAIR COLUMN PERMUTATION (partners in-register, packed u32 stores).
// ---------------------------------------------------------------------------
__device__ __forceinline__ int bperm(int row) {
    const int p = row & 63;
    const int j = p >> 4, l = p & 15;
    return (row & ~63) | ((j & 1) + 2 * l + 32 * (j >> 1));
}

__global__ __launch_bounds__(256) void gemm_qkv_mfma_kernel(
    const u16* __restrict__ A, int lda,
    const u16* __restrict__ BT,
    const float* __restrict__ bias,
    const float* __restrict__ cosb, const float* __restrict__ sinb,
    const float* __restrict__ qn, const float* __restrict__ kn,
    u16* __restrict__ C, int ldc, int K)
{
    __shared__ u16 sA[2][128 * 32];
    __shared__ u16 sB[2][128 * 32];
    const int tid = threadIdx.x;
    const int lane = tid & 63;
    const int wave = tid >> 6;
    const int wy = wave >> 1, wx = wave & 1;
    const int l16 = lane & 15, quad = lane >> 4;

    // XCD swizzle: consecutive ids round-robin XCDs; give each XCD a
    // contiguous chunk of tile space (72 tiles = 4 m-rows) for L2 locality.
    int id = blockIdx.x;
    id = (id & 7) * 72 + (id >> 3);        // 576/8 = 72
    const int m0 = (id / 18) * 128, n0 = (id % 18) * 128;

    // staging indices (2 granules each of A and B per thread)
    const int srow0 = tid >> 2,         sg0 = tid & 3;
    const int srow1 = (tid + 256) >> 2, sg1 = tid & 3;   // f = tid+256

    // permuted B source rows (RoPE-pair layout)
    const int brow0 = bperm(n0 + srow0);
    const int brow1 = bperm(n0 + srow1);

    f32x4 acc[4][4] = {};
    const int NK = K / 32;

    // prologue: stage k-step 0 into buffer 0
    load_lds16(A  + (size_t)(m0 + srow0) * lda + sg0 * 8, &sA[0][tid * 8]);
    load_lds16(BT + (size_t)brow0 * K          + sg0 * 8, &sB[0][tid * 8]);
    load_lds16(A  + (size_t)(m0 + srow1) * lda + sg1 * 8, &sA[0][(tid + 256) * 8]);
    load_lds16(BT + (size_t)brow1 * K          + sg1 * 8, &sB[0][(tid + 256) * 8]);

    for (int kt = 0; kt < NK; kt++) {
        const int cur = kt & 1;
        __syncthreads();   // DMA into buf[cur] complete; prior reads of buf[cur^1] done
        if (kt + 1 < NK) {
            const int nxt = cur ^ 1;
            const int k0 = (kt + 1) * 32;
            load_lds16(A  + (size_t)(m0 + srow0) * lda + k0 + sg0 * 8, &sA[nxt][tid * 8]);
            load_lds16(BT + (size_t)brow0 * K          + k0 + sg0 * 8, &sB[nxt][tid * 8]);
            load_lds16(A  + (size_t)(m0 + srow1) * lda + k0 + sg1 * 8, &sA[nxt][(tid + 256) * 8]);
            load_lds16(BT + (size_t)brow1 * K          + k0 + sg1 * 8, &sB[nxt][(tid + 256) * 8]);
        }

        bf16x8 af[4], bfr[4];
        #pragma unroll
        for (int i = 0; i < 4; i++) {
            af[i]  = *reinterpret_cast<const bf16x8*>(
                &sA[cur][(wy * 64 + i * 16 + l16) * 32 + quad * 8]);
            bfr[i] = *reinterpret_cast<const bf16x8*>(
                &sB[cur][(wx * 64 + i * 16 + l16) * 32 + quad * 8]);
        }
        #pragma unroll
        for (int i = 0; i < 4; i++)
            #pragma unroll
            for (int j = 0; j < 4; j++)
                acc[i][j] = __builtin_amdgcn_mfma_f32_16x16x32_bf16(
                    af[i], bfr[j], acc[i][j], 0, 0, 0);
    }

    // ---- fused epilogue (thread holds logical cols 2*l16,2*l16+1,32+2*l16,33+2*l16) ----
    const int cb = (n0 + wx * 64) >> 6;   // 64-col block, 0..35
    const int s  = cb / 12;               // 0=q, 1=k, 2=v
    const int colbase = n0 + wx * 64;
    // logical col offsets within head for j=0..3
    const int d0 = 2 * l16, d1 = 2 * l16 + 1, d2 = 2 * l16 + 32, d3 = 2 * l16 + 33;
    float bv[4];
    bv[0] = bias[colbase + d0]; bv[1] = bias[colbase + d1];
    bv[2] = bias[colbase + d2]; bv[3] = bias[colbase + d3];
    float wv[4];
    if (s < 2) {
        const float* wn = (s == 0) ? qn : kn;
        wv[0] = wn[d0]; wv[1] = wn[d1]; wv[2] = wn[d2]; wv[3] = wn[d3];
    }

    #pragma unroll
    for (int i = 0; i < 4; i++) {
        #pragma unroll
        for (int r = 0; r < 4; r++) {
            const int row = m0 + wy * 64 + i * 16 + quad * 4 + r;
            float v[4];
            #pragma unroll
            for (int j = 0; j < 4; j++) v[j] = acc[i][j][r] + bv[j];

            if (s < 2) {
                float sq = v[0]*v[0] + v[1]*v[1] + v[2]*v[2] + v[3]*v[3];
                #pragma unroll
                for (int off = 1; off < 16; off <<= 1)
                    sq += __shfl_xor(sq, off, 64);
                const float rms = rsqrtf(sq * (1.0f / 64.0f) + 1e-6f);
                const int n = row & (SEQ - 1);
                const float nv0 = v[0] * rms * wv[0];
                const float nv1 = v[1] * rms * wv[1];
                const float nv2 = v[2] * rms * wv[2];
                const float nv3 = v[3] * rms * wv[3];
                const float c0 = cosb[n * 32 + l16],      s0 = sinb[n * 32 + l16];
                const float c1 = cosb[n * 32 + 16 + l16], s1 = sinb[n * 32 + 16 + l16];
                v[0] = nv0 * c0 - nv1 * s0;
                v[1] = nv0 * s0 + nv1 * c0;
                v[2] = nv2 * c1 - nv3 * s1;
                v[3] = nv2 * s1 + nv3 * c1;
                if (s == 0) {
                    // fold Dh^-0.5 * log2(e) into q: scores land in exp2 domain
                    v[0] *= 0.18033688011112042f; v[1] *= 0.18033688011112042f;
                    v[2] *= 0.18033688011112042f; v[3] *= 0.18033688011112042f;
                }
            }
            u32* cw = reinterpret_cast<u32*>(&C[(size_t)row * ldc + colbase]);
            cw[l16]      = cvt_pk_bf16(v[0], v[1]);   // u16 cols 2*l16, 2*l16+1
            cw[16 + l16] = cvt_pk_bf16(v[2], v[3]);   // u16 cols 32+2*l16, 33+2*l16
        }
    }
}

// ---------------------------------------------------------------------------
// bf16 MFMA GEMM 64x64 BK32, double-buffered, fp32 output + bias.
// 1-D grid (768 blocks) with XCD-aware swizzle (768%8==0, bijective).
// ---------------------------------------------------------------------------
__global__ __launch_bounds__(256) void gemm_proj_mfma_kernel(
    const u16* __restrict__ A, int lda,
    const u16* __restrict__ BT,
    const float* __restrict__ bias,
    float* __restrict__ C, int ldc, int K)
{
    __shared__ u16 sA[2][64 * 32];
    __shared__ u16 sB[2][64 * 32];
    const int tid = threadIdx.x;
    const int lane = tid & 63;
    const int wave = tid >> 6;
    const int l16 = lane & 15, quad = lane >> 4;

    int id = blockIdx.x;
    id = (id & 7) * 96 + (id >> 3);        // 768/8 = 96
    const int m0 = (id / 12) * 64, n0 = (id % 12) * 64;

    const int srow = tid >> 2, sg = tid & 3;   // 256 granules per matrix

    f32x4 acc[4] = {};
    const int NK = K / 32;

    load_lds16(A  + (size_t)(m0 + srow) * lda + sg * 8, &sA[0][tid * 8]);
    load_lds16(BT + (size_t)(n0 + srow) * K   + sg * 8, &sB[0][tid * 8]);

    for (int kt = 0; kt < NK; kt++) {
        const int cur = kt & 1;
        __syncthreads();
        if (kt + 1 < NK) {
            const int nxt = cur ^ 1;
            const int k0 = (kt + 1) * 32;
            load_lds16(A  + (size_t)(m0 + srow) * lda + k0 + sg * 8, &sA[nxt][tid * 8]);
            load_lds16(BT + (size_t)(n0 + srow) * K   + k0 + sg * 8, &sB[nxt][tid * 8]);
        }

        const bf16x8 af = *reinterpret_cast<const bf16x8*>(
            &sA[cur][(wave * 16 + l16) * 32 + quad * 8]);
        bf16x8 bfr[4];
        #pragma unroll
        for (int j = 0; j < 4; j++)
            bfr[j] = *reinterpret_cast<const bf16x8*>(
                &sB[cur][(j * 16 + l16) * 32 + quad * 8]);
        #pragma unroll
        for (int j = 0; j < 4; j++)
            acc[j] = __builtin_amdgcn_mfma_f32_16x16x32_bf16(
                af, bfr[j], acc[j], 0, 0, 0);
    }

    float bv[4];
    #pragma unroll
    for (int j = 0; j < 4; j++) bv[j] = bias[n0 + j * 16 + l16];
    #pragma unroll
    for (int r = 0; r < 4; r++) {
        const int row = m0 + wave * 16 + quad * 4 + r;
        #pragma unroll
        for (int j = 0; j < 4; j++) {
            const int col = n0 + j * 16 + l16;
            C[(size_t)row * ldc + col] = acc[j][r] + bv[j];
        }
    }
}

// ---------------------------------------------------------------------------
// Flash MFMA attention, S^T-oriented, XOR-chunk-swizzled P buffer.
// V5 sVt32 bank swizzle: sigma(h) = 4h ^ 16*(h&1) -> PV reads span all 32
// banks (conflict-free); writes stay 2 lanes/bank (free).
// V7: PREFETCH ISSUED AFTER THE BARRIER (T14 issue-early/write-late).
// Old order issued the 4 global loads right before __syncthreads, whose
// vmcnt(0) drain exposed full L2/HBM latency every tile. Now: stage(t) ->
// barrier (0 outstanding VMEM, free drain) -> issue prefetch(t+1) ->
// compute(t) (~3000 cyc) hides the load latency; stage(t+1)'s register
// reads find data complete. Pure reordering: identical dataflow/numerics.
// ---------------------------------------------------------------------------
#define KP 80   // sK stride (u16)

__global__ __launch_bounds__(256) void attn_mfma_kernel(u16* __restrict__ qkvb)
{
    const int qt = blockIdx.x;   // q tile (64 rows)
    const int h  = blockIdx.y;
    const int b  = blockIdx.z;
    const int tid  = threadIdx.x;
    const int wave = tid >> 6;
    const int lane = tid & 63;
    const int l16  = lane & 15;
    const int quad = lane >> 4;

    const size_t bb = (size_t)b * SEQ * QKV_N;
    const u16* Kg = qkvb + bb + CDIM     + h * DHEAD;
    const u16* Vg = qkvb + bb + 2 * CDIM + h * DHEAD;
    const u16* Qg = qkvb + bb + (size_t)(qt * 64) * QKV_N + h * DHEAD;

    __shared__ u16 sK[2][64 * KP];
    __shared__ u32 sVt32[2][64 * 32];
    __shared__ u32x2 sP2[64 * 16];   // [q][chunk^l16], 8B chunks, wave-private rows

    const int kq = tid >> 3;      // K rows kq, kq+32
    const int g  = tid & 7;       // 16B granule (d = g*8..g*8+7)
    const int kp = tid >> 3;      // V key pair: rows 2kp, 2kp+1

    bf16x8 qf[2];
    {
        const u16* qrow = Qg + (size_t)(wave * 16 + l16) * QKV_N;
        qf[0] = *reinterpret_cast<const bf16x8*>(qrow + quad * 8);
        qf[1] = *reinterpret_cast<const bf16x8*>(qrow + 32 + quad * 8);
    }

    f32x4 O[4] = {};        // O^T: rows d, cols q (l16)
    float l_acc = 0.f;

    bf16x8 kreg[2], vreg[2];
    kreg[0] = *reinterpret_cast<const bf16x8*>(Kg + (size_t)(kq)      * QKV_N + g * 8);
    kreg[1] = *reinterpret_cast<const bf16x8*>(Kg + (size_t)(kq + 32) * QKV_N + g * 8);
    vreg[0] = *reinterpret_cast<const bf16x8*>(Vg + (size_t)(2 * kp)     * QKV_N + g * 8);
    vreg[1] = *reinterpret_cast<const bf16x8*>(Vg + (size_t)(2 * kp + 1) * QKV_N + g * 8);

    const int prow = (wave * 16 + l16) * 16;

    for (int t = 0; t < SEQ / 64; t++) {
        const int cur = t & 1;
        // stage tile t from prefetched regs (forces wait on t's loads,
        // which have had the whole previous compute phase to complete)
        *reinterpret_cast<bf16x8*>(&sK[cur][kq * KP + g * 8])        = kreg[0];
        *reinterpret_cast<bf16x8*>(&sK[cur][(kq + 32) * KP + g * 8]) = kreg[1];
        // sigma(g) = 4g ^ 16*(g&1): toggles bank-bit4 on odd d-groups so PV
        // reads span all 32 banks; writes stay 2 lanes/bank (free).
        const int pwv = kp ^ (4 * g) ^ ((g & 1) << 4);
        {
            // pack V[2kp][d] (low16) | V[2kp+1][d] (high16), one v_perm_b32 each
            const u32* v0w = reinterpret_cast<const u32*>(&vreg[0]);
            const u32* v1w = reinterpret_cast<const u32*>(&vreg[1]);
            #pragma unroll
            for (int e = 0; e < 8; e++) {
                const u32 pack = __builtin_amdgcn_perm(
                    v1w[e >> 1], v0w[e >> 1],
                    (e & 1) ? 0x07060302u : 0x05040100u);
                sVt32[cur][(g * 8 + e) * 32 + pwv] = pack;
            }
        }
        __syncthreads();   // no outstanding VMEM here -> drain is free

        // issue prefetch(t+1) AFTER the barrier: latency hides under compute(t)
        if (t + 1 < SEQ / 64) {
            const size_t base = (size_t)(t + 1) * 64;
            kreg[0] = *reinterpret_cast<const bf16x8*>(Kg + (base + kq)      * QKV_N + g * 8);
            kreg[1] = *reinterpret_cast<const bf16x8*>(Kg + (base + kq + 32) * QKV_N + g * 8);
            vreg[0] = *reinterpret_cast<const bf16x8*>(Vg + (base + 2 * kp)     * QKV_N + g * 8);
            vreg[1] = *reinterpret_cast<const bf16x8*>(Vg + (base + 2 * kp + 1) * QKV_N + g * 8);
        }

        // S^T = K Qs^T: rows = keys (kt*16 + quad*4 + r), cols = q (l16)
        f32x4 s[4];
        __builtin_amdgcn_s_setprio(1);
        #pragma unroll
        for (int kt = 0; kt < 4; kt++) {
            bf16x8 kf0 = *reinterpret_cast<const bf16x8*>(
                &sK[cur][(kt * 16 + l16) * KP + quad * 8]);
            bf16x8 kf1 = *reinterpret_cast<const bf16x8*>(
                &sK[cur][(kt * 16 + l16) * KP + 32 + quad * 8]);
            f32x4 a = {};
            a = __builtin_amdgcn_mfma_f32_16x16x32_bf16(kf0, qf[0], a, 0, 0, 0);
            a = __builtin_amdgcn_mfma_f32_16x16x32_bf16(kf1, qf[1], a, 0, 0, 0);
            s[kt] = a;
        }
        __builtin_amdgcn_s_setprio(0);

        // P = exp2(S), split into halves to overlap TRANS with LDS latency.
        union { struct { u32x2 lo, hi; } s2; bf16x8 v; } pu0, pu1;

        // half 0: keys 0..31 (kt = 0,1)
        #pragma unroll
        for (int kt = 0; kt < 2; kt++) {
            float p0 = EXP2(s[kt][0]);
            float p1 = EXP2(s[kt][1]);
            float p2 = EXP2(s[kt][2]);
            float p3 = EXP2(s[kt][3]);
            l_acc += p0; l_acc += p1; l_acc += p2; l_acc += p3;
            u32x2 pk;
            pk.x = cvt_pk_bf16(p0, p1);
            pk.y = cvt_pk_bf16(p2, p3);
            sP2[prow + ((kt * 4 + quad) ^ l16)] = pk;   // keys kt*16+quad*4..+3
        }
        // issue pu0 reads; latency hidden by half-1 exp/pack below
        pu0.s2.lo = sP2[prow + ((2 * quad)     ^ l16)];   // keys quad*8..+3
        pu0.s2.hi = sP2[prow + ((2 * quad + 1) ^ l16)];   // keys quad*8+4..+7

        // half 1: keys 32..63 (kt = 2,3)
        #pragma unroll
        for (int kt = 2; kt < 4; kt++) {
            float p0 = EXP2(s[kt][0]);
            float p1 = EXP2(s[kt][1]);
            float p2 = EXP2(s[kt][2]);
            float p3 = EXP2(s[kt][3]);
            l_acc += p0; l_acc += p1; l_acc += p2; l_acc += p3;
            u32x2 pk;
            pk.x = cvt_pk_bf16(p0, p1);
            pk.y = cvt_pk_bf16(p2, p3);
            sP2[prow + ((kt * 4 + quad) ^ l16)] = pk;
        }
        pu1.s2.lo = sP2[prow + ((8 + 2 * quad) ^ l16)];   // keys 32+quad*8..+3
        pu1.s2.hi = sP2[prow + ((9 + 2 * quad) ^ l16)];   // keys 32+quad*8+4..+7

        // O^T += V^T P^T; half0 MFMAs overlap pu1 read latency.
        __builtin_amdgcn_s_setprio(1);
        #pragma unroll
        for (int dt = 0; dt < 4; dt++) {
            const int row = dt * 16 + l16;
            const int hr  = (row >> 3) & 7;
            const int sw  = (4 * hr) ^ ((hr & 1) << 4);
            bf16x8 vf0 = *reinterpret_cast<const bf16x8*>(
                &sVt32[cur][row * 32 + ((quad * 4) ^ sw)]);
            O[dt] = __builtin_amdgcn_mfma_f32_16x16x32_bf16(vf0, pu0.v, O[dt], 0, 0, 0);
        }
        #pragma unroll
        for (int dt = 0; dt < 4; dt++) {
            const int row = dt * 16 + l16;
            const int hr  = (row >> 3) & 7;
            const int sw  = (4 * hr) ^ ((hr & 1) << 4);
            bf16x8 vf1 = *reinterpret_cast<const bf16x8*>(
                &sVt32[cur][row * 32 + ((16 + quad * 4) ^ sw)]);
            O[dt] = __builtin_amdgcn_mfma_f32_16x16x32_bf16(vf1, pu1.v, O[dt], 0, 0, 0);
        }
        __builtin_amdgcn_s_setprio(0);
    }

    // epilogue: reduce l over quads, write O^T/l to q slot
    float lv = l_acc;
    lv += __shfl_xor(lv, 16, 64);
    lv += __shfl_xor(lv, 32, 64);
    const float inv = 1.0f / lv;
    const int qrow = qt * 64 + wave * 16 + l16;
    u16* orow = qkvb + bb + (size_t)qrow * QKV_N + h * DHEAD;
    #pragma unroll
    for (int dt = 0; dt < 4; dt++) {
        u32x2 pk;
        pk.x = cvt_pk_bf16(O[dt][0] * inv, O[dt][1] * inv);
        pk.y = cvt_pk_bf16(O[dt][2] * inv, O[dt][3] * inv);
        *reinterpret_cast<u32x2*>(&orow[dt * 16 + quad * 4]) = pk;
    }
}

// ---------------------------------------------------------------------------
extern "C" void kernel_launch(void* const* d_in, const int* in_sizes, int n_in,
                              void* d_out, int out_size, void* d_ws, size_t ws_size,
                              hipStream_t stream)
{
    const float* x      = (const float*)d_in[0];
    const float* cosb   = (const float*)d_in[1];
    const float* sinb   = (const float*)d_in[2];
    const float* qkv_w  = (const float*)d_in[3];
    const float* qkv_b  = (const float*)d_in[4];
    const float* proj_w = (const float*)d_in[5];
    const float* proj_b = (const float*)d_in[6];
    const float* qn_w   = (const float*)d_in[7];
    const float* kn_w   = (const float*)d_in[8];
    float* out = (float*)d_out;

    char* ws = (char*)d_ws;
    u16* qkvb = (u16*)(ws);                    // 4096 x 2304 bf16 = 18,874,368 B
    u16* xb   = (u16*)(ws + 18874368);         // 4096 x 768  bf16 =  6,291,456 B
    u16* wT   = (u16*)(ws + 25165824);         // 2304 x 768  bf16 =  3,538,944 B
    u16* pwT  = (u16*)(ws + 28704768);         //  768 x 768  bf16 =  1,179,648 B

    // 0. fused prep: x->bf16, both weight transposes
    prep_kernel<<<PREP_CONV + PREP_TQ + PREP_TP, 256, 0, stream>>>(
        x, xb, qkv_w, wT, proj_w, pwT);

    // 1. QKV projection + fused RMSNorm/RoPE -> bf16 qkv buffer (dbuf)
    gemm_qkv_mfma_kernel<<<576, 256, 0, stream>>>(
        xb, CDIM, wT, qkv_b, cosb, sinb, qn_w, kn_w, qkvb, QKV_N, CDIM);

    // 2. Flash MFMA attention (out -> q slot of qkvb)
    attn_mfma_kernel<<<dim3(SEQ / 64, HEADS, BATCH), 256, 0, stream>>>(qkvb);

    // 3. Output projection (bf16 MFMA 64x64 dbuf, fp32 out)
    gemm_proj_mfma_kernel<<<768, 256, 0, stream>>>(
        qkvb, QKV_N, pwT, proj_b, out, CDIM, CDIM);
}

// Round 7
// 171.358 us; speedup vs baseline: 1.0230x; 1.0230x over previous
//
#include <hip/hip_runtime.h>
#include <hip/hip_bf16.h>

// Problem constants
#define BATCH 2
#define SEQ   2048
#define CDIM  768
#define HEADS 12
#define DHEAD 64
#define QKV_N 2304   // 3*CDIM
#define ROWS  4096   // BATCH*SEQ

typedef unsigned short u16;
typedef unsigned int   u32;
typedef __attribute__((ext_vector_type(4))) float f32x4;
typedef __attribute__((ext_vector_type(8))) short bf16x8;
typedef __attribute__((ext_vector_type(2))) unsigned int u32x2;

// fp32 -> bf16 (RNE) bit pattern
__device__ __forceinline__ u16 f2b(float f) {
    union { float f; unsigned u; } v; v.f = f;
    unsigned r = v.u + 0x7FFF + ((v.u >> 16) & 1u);
    return (u16)(r >> 16);
}
// bf16 bits -> fp32
__device__ __forceinline__ float b2f(u16 u) {
    union { unsigned i; float f; } x;
    x.i = ((unsigned)u) << 16;
    return x.f;
}
// pack two fp32 -> one u32 of 2x bf16 (RNE), single VALU instruction.
__device__ __forceinline__ u32 cvt_pk_bf16(float lo, float hi) {
    u32 r;
    asm("v_cvt_pk_bf16_f32 %0, %1, %2" : "=v"(r) : "v"(lo), "v"(hi));
    return r;
}

// exp2: native v_exp_f32 when builtin available
#if __has_builtin(__builtin_amdgcn_exp2f)
#define EXP2(x) __builtin_amdgcn_exp2f(x)
#else
#define EXP2(x) __expf((x) * 0.69314718056f)
#endif

// async global->LDS 16B copy
__device__ __forceinline__ void load_lds16(const void* g, void* l) {
    __builtin_amdgcn_global_load_lds(
        (const __attribute__((address_space(1))) u32*)g,
        (__attribute__((address_space(3))) u32*)l, 16, 0, 0);
}

// ---------------------------------------------------------------------------
// Fused prep: x->bf16 (blocks [0,3072)), qkv_w transpose-convert
// (blocks [3072,4800)), proj_w transpose-convert (blocks [4800,5376)).
// ---------------------------------------------------------------------------
#define PREP_CONV 3072          // 4096*768/4 float4 / 256
#define PREP_TQ   1728          // (2304/32) x (768/32)
#define PREP_TP   576           // (768/32) x (768/32)

__device__ __forceinline__ void tconv_body(
    const float* __restrict__ in, u16* __restrict__ out, int R, int C,
    int bi, int bj)
{
    __shared__ float t[32][33];
    const int c = threadIdx.x & 31, r0 = threadIdx.x >> 5;
    #pragma unroll
    for (int i = 0; i < 4; i++) {
        const int r = r0 + i * 8;
        t[r][c] = in[(size_t)(bi * 32 + r) * C + bj * 32 + c];
    }
    __syncthreads();
    #pragma unroll
    for (int i = 0; i < 4; i++) {
        const int r = r0 + i * 8;
        out[(size_t)(bj * 32 + r) * R + bi * 32 + c] = f2b(t[c][r]);
    }
}

__global__ __launch_bounds__(256) void prep_kernel(
    const float* __restrict__ x, u16* __restrict__ xb,
    const float* __restrict__ qkv_w, u16* __restrict__ wT,
    const float* __restrict__ proj_w, u16* __restrict__ pwT)
{
    const int bid = blockIdx.x;
    if (bid < PREP_CONV) {
        const int i = bid * 256 + threadIdx.x;
        const float4 v = reinterpret_cast<const float4*>(x)[i];
        ushort4 o;
        o.x = f2b(v.x); o.y = f2b(v.y); o.z = f2b(v.z); o.w = f2b(v.w);
        reinterpret_cast<ushort4*>(xb)[i] = o;
    } else if (bid < PREP_CONV + PREP_TQ) {
        const int t = bid - PREP_CONV;
        tconv_body(qkv_w, wT, CDIM, QKV_N, t / 72, t % 72);
    } else {
        const int t = bid - PREP_CONV - PREP_TQ;
        tconv_body(proj_w, pwT, CDIM, CDIM, t / 24, t % 24);
    }
}

// ---------------------------------------------------------------------------
// bf16 MFMA GEMM 128x128 BK32, DOUBLE-BUFFERED LDS (1 barrier/K-step),
// + FUSED RMSNorm + RoPE epilogue. q pre-scaled by Dh^-0.5 * log2(e).
// 1-D grid (576 blocks) with XCD-aware swizzle: 576%8==0, bijective remap.
// V6: RoPE-PAIR COLUMN PERMUTATION (partners in-register, packed u32 stores).
// ---------------------------------------------------------------------------
__device__ __forceinline__ int bperm(int row) {
    const int p = row & 63;
    const int j = p >> 4, l = p & 15;
    return (row & ~63) | ((j & 1) + 2 * l + 32 * (j >> 1));
}

__global__ __launch_bounds__(256) void gemm_qkv_mfma_kernel(
    const u16* __restrict__ A, int lda,
    const u16* __restrict__ BT,
    const float* __restrict__ bias,
    const float* __restrict__ cosb, const float* __restrict__ sinb,
    const float* __restrict__ qn, const float* __restrict__ kn,
    u16* __restrict__ C, int ldc, int K)
{
    __shared__ u16 sA[2][128 * 32];
    __shared__ u16 sB[2][128 * 32];
    const int tid = threadIdx.x;
    const int lane = tid & 63;
    const int wave = tid >> 6;
    const int wy = wave >> 1, wx = wave & 1;
    const int l16 = lane & 15, quad = lane >> 4;

    // XCD swizzle: consecutive ids round-robin XCDs; give each XCD a
    // contiguous chunk of tile space (72 tiles = 4 m-rows) for L2 locality.
    int id = blockIdx.x;
    id = (id & 7) * 72 + (id >> 3);        // 576/8 = 72
    const int m0 = (id / 18) * 128, n0 = (id % 18) * 128;

    // staging indices (2 granules each of A and B per thread)
    const int srow0 = tid >> 2,         sg0 = tid & 3;
    const int srow1 = (tid + 256) >> 2, sg1 = tid & 3;   // f = tid+256

    // permuted B source rows (RoPE-pair layout)
    const int brow0 = bperm(n0 + srow0);
    const int brow1 = bperm(n0 + srow1);

    f32x4 acc[4][4] = {};
    const int NK = K / 32;

    // prologue: stage k-step 0 into buffer 0
    load_lds16(A  + (size_t)(m0 + srow0) * lda + sg0 * 8, &sA[0][tid * 8]);
    load_lds16(BT + (size_t)brow0 * K          + sg0 * 8, &sB[0][tid * 8]);
    load_lds16(A  + (size_t)(m0 + srow1) * lda + sg1 * 8, &sA[0][(tid + 256) * 8]);
    load_lds16(BT + (size_t)brow1 * K          + sg1 * 8, &sB[0][(tid + 256) * 8]);

    for (int kt = 0; kt < NK; kt++) {
        const int cur = kt & 1;
        __syncthreads();   // DMA into buf[cur] complete; prior reads of buf[cur^1] done
        if (kt + 1 < NK) {
            const int nxt = cur ^ 1;
            const int k0 = (kt + 1) * 32;
            load_lds16(A  + (size_t)(m0 + srow0) * lda + k0 + sg0 * 8, &sA[nxt][tid * 8]);
            load_lds16(BT + (size_t)brow0 * K          + k0 + sg0 * 8, &sB[nxt][tid * 8]);
            load_lds16(A  + (size_t)(m0 + srow1) * lda + k0 + sg1 * 8, &sA[nxt][(tid + 256) * 8]);
            load_lds16(BT + (size_t)brow1 * K          + k0 + sg1 * 8, &sB[nxt][(tid + 256) * 8]);
        }

        bf16x8 af[4], bfr[4];
        #pragma unroll
        for (int i = 0; i < 4; i++) {
            af[i]  = *reinterpret_cast<const bf16x8*>(
                &sA[cur][(wy * 64 + i * 16 + l16) * 32 + quad * 8]);
            bfr[i] = *reinterpret_cast<const bf16x8*>(
                &sB[cur][(wx * 64 + i * 16 + l16) * 32 + quad * 8]);
        }
        #pragma unroll
        for (int i = 0; i < 4; i++)
            #pragma unroll
            for (int j = 0; j < 4; j++)
                acc[i][j] = __builtin_amdgcn_mfma_f32_16x16x32_bf16(
                    af[i], bfr[j], acc[i][j], 0, 0, 0);
    }

    // ---- fused epilogue (thread holds logical cols 2*l16,2*l16+1,32+2*l16,33+2*l16) ----
    const int cb = (n0 + wx * 64) >> 6;   // 64-col block, 0..35
    const int s  = cb / 12;               // 0=q, 1=k, 2=v
    const int colbase = n0 + wx * 64;
    // logical col offsets within head for j=0..3
    const int d0 = 2 * l16, d1 = 2 * l16 + 1, d2 = 2 * l16 + 32, d3 = 2 * l16 + 33;
    float bv[4];
    bv[0] = bias[colbase + d0]; bv[1] = bias[colbase + d1];
    bv[2] = bias[colbase + d2]; bv[3] = bias[colbase + d3];
    float wv[4];
    if (s < 2) {
        const float* wn = (s == 0) ? qn : kn;
        wv[0] = wn[d0]; wv[1] = wn[d1]; wv[2] = wn[d2]; wv[3] = wn[d3];
    }

    #pragma unroll
    for (int i = 0; i < 4; i++) {
        #pragma unroll
        for (int r = 0; r < 4; r++) {
            const int row = m0 + wy * 64 + i * 16 + quad * 4 + r;
            float v[4];
            #pragma unroll
            for (int j = 0; j < 4; j++) v[j] = acc[i][j][r] + bv[j];

            if (s < 2) {
                float sq = v[0]*v[0] + v[1]*v[1] + v[2]*v[2] + v[3]*v[3];
                #pragma unroll
                for (int off = 1; off < 16; off <<= 1)
                    sq += __shfl_xor(sq, off, 64);
                const float rms = rsqrtf(sq * (1.0f / 64.0f) + 1e-6f);
                const int n = row & (SEQ - 1);
                const float nv0 = v[0] * rms * wv[0];
                const float nv1 = v[1] * rms * wv[1];
                const float nv2 = v[2] * rms * wv[2];
                const float nv3 = v[3] * rms * wv[3];
                const float c0 = cosb[n * 32 + l16],      s0 = sinb[n * 32 + l16];
                const float c1 = cosb[n * 32 + 16 + l16], s1 = sinb[n * 32 + 16 + l16];
                v[0] = nv0 * c0 - nv1 * s0;
                v[1] = nv0 * s0 + nv1 * c0;
                v[2] = nv2 * c1 - nv3 * s1;
                v[3] = nv2 * s1 + nv3 * c1;
                if (s == 0) {
                    // fold Dh^-0.5 * log2(e) into q: scores land in exp2 domain
                    v[0] *= 0.18033688011112042f; v[1] *= 0.18033688011112042f;
                    v[2] *= 0.18033688011112042f; v[3] *= 0.18033688011112042f;
                }
            }
            u32* cw = reinterpret_cast<u32*>(&C[(size_t)row * ldc + colbase]);
            cw[l16]      = cvt_pk_bf16(v[0], v[1]);   // u16 cols 2*l16, 2*l16+1
            cw[16 + l16] = cvt_pk_bf16(v[2], v[3]);   // u16 cols 32+2*l16, 33+2*l16
        }
    }
}

// ---------------------------------------------------------------------------
// bf16 MFMA GEMM 64x64 BK32, double-buffered, fp32 output + bias.
// 1-D grid (768 blocks) with XCD-aware swizzle (768%8==0, bijective).
// ---------------------------------------------------------------------------
__global__ __launch_bounds__(256) void gemm_proj_mfma_kernel(
    const u16* __restrict__ A, int lda,
    const u16* __restrict__ BT,
    const float* __restrict__ bias,
    float* __restrict__ C, int ldc, int K)
{
    __shared__ u16 sA[2][64 * 32];
    __shared__ u16 sB[2][64 * 32];
    const int tid = threadIdx.x;
    const int lane = tid & 63;
    const int wave = tid >> 6;
    const int l16 = lane & 15, quad = lane >> 4;

    int id = blockIdx.x;
    id = (id & 7) * 96 + (id >> 3);        // 768/8 = 96
    const int m0 = (id / 12) * 64, n0 = (id % 12) * 64;

    const int srow = tid >> 2, sg = tid & 3;   // 256 granules per matrix

    f32x4 acc[4] = {};
    const int NK = K / 32;

    load_lds16(A  + (size_t)(m0 + srow) * lda + sg * 8, &sA[0][tid * 8]);
    load_lds16(BT + (size_t)(n0 + srow) * K   + sg * 8, &sB[0][tid * 8]);

    for (int kt = 0; kt < NK; kt++) {
        const int cur = kt & 1;
        __syncthreads();
        if (kt + 1 < NK) {
            const int nxt = cur ^ 1;
            const int k0 = (kt + 1) * 32;
            load_lds16(A  + (size_t)(m0 + srow) * lda + k0 + sg * 8, &sA[nxt][tid * 8]);
            load_lds16(BT + (size_t)(n0 + srow) * K   + k0 + sg * 8, &sB[nxt][tid * 8]);
        }

        const bf16x8 af = *reinterpret_cast<const bf16x8*>(
            &sA[cur][(wave * 16 + l16) * 32 + quad * 8]);
        bf16x8 bfr[4];
        #pragma unroll
        for (int j = 0; j < 4; j++)
            bfr[j] = *reinterpret_cast<const bf16x8*>(
                &sB[cur][(j * 16 + l16) * 32 + quad * 8]);
        #pragma unroll
        for (int j = 0; j < 4; j++)
            acc[j] = __builtin_amdgcn_mfma_f32_16x16x32_bf16(
                af, bfr[j], acc[j], 0, 0, 0);
    }

    float bv[4];
    #pragma unroll
    for (int j = 0; j < 4; j++) bv[j] = bias[n0 + j * 16 + l16];
    #pragma unroll
    for (int r = 0; r < 4; r++) {
        const int row = m0 + wave * 16 + quad * 4 + r;
        #pragma unroll
        for (int j = 0; j < 4; j++) {
            const int col = n0 + j * 16 + l16;
            C[(size_t)row * ldc + col] = acc[j][r] + bv[j];
        }
    }
}

// ---------------------------------------------------------------------------
// Flash MFMA attention, S^T-oriented, XOR-chunk-swizzled P buffer.
// V8 = R5 loop order (prefetch BEFORE barrier — R6's reorder regressed,
// reverted) + sK PAD->SWIZZLE: KP 80->64 with 16B-granule XOR swizzle
// (granule ^= row&7 on both write and read; reads/writes stay at the
// 8-words/bank b128 optimum). LDS: 45056 -> 40960 B = exactly 4 blocks/CU
// (16 waves/CU, +33% occupancy for this latency-bound kernel).
// sVt32 swizzle: sigma(h) = 4h ^ 16*(h&1) (round-4 fix, conflict-free).
// ---------------------------------------------------------------------------
__global__ __launch_bounds__(256) void attn_mfma_kernel(u16* __restrict__ qkvb)
{
    const int qt = blockIdx.x;   // q tile (64 rows)
    const int h  = blockIdx.y;
    const int b  = blockIdx.z;
    const int tid  = threadIdx.x;
    const int wave = tid >> 6;
    const int lane = tid & 63;
    const int l16  = lane & 15;
    const int quad = lane >> 4;

    const size_t bb = (size_t)b * SEQ * QKV_N;
    const u16* Kg = qkvb + bb + CDIM     + h * DHEAD;
    const u16* Vg = qkvb + bb + 2 * CDIM + h * DHEAD;
    const u16* Qg = qkvb + bb + (size_t)(qt * 64) * QKV_N + h * DHEAD;

    __shared__ u16 sK[2][64 * 64];   // granule-XOR swizzled, no pad
    __shared__ u32 sVt32[2][64 * 32];
    __shared__ u32x2 sP2[64 * 16];   // [q][chunk^l16], 8B chunks, wave-private rows

    const int kq = tid >> 3;      // K rows kq, kq+32
    const int g  = tid & 7;       // 16B granule (d = g*8..g*8+7)
    const int kp = tid >> 3;      // V key pair: rows 2kp, 2kp+1

    bf16x8 qf[2];
    {
        const u16* qrow = Qg + (size_t)(wave * 16 + l16) * QKV_N;
        qf[0] = *reinterpret_cast<const bf16x8*>(qrow + quad * 8);
        qf[1] = *reinterpret_cast<const bf16x8*>(qrow + 32 + quad * 8);
    }

    f32x4 O[4] = {};        // O^T: rows d, cols q (l16)
    float l_acc = 0.f;

    bf16x8 kreg[2], vreg[2];
    kreg[0] = *reinterpret_cast<const bf16x8*>(Kg + (size_t)(kq)      * QKV_N + g * 8);
    kreg[1] = *reinterpret_cast<const bf16x8*>(Kg + (size_t)(kq + 32) * QKV_N + g * 8);
    vreg[0] = *reinterpret_cast<const bf16x8*>(Vg + (size_t)(2 * kp)     * QKV_N + g * 8);
    vreg[1] = *reinterpret_cast<const bf16x8*>(Vg + (size_t)(2 * kp + 1) * QKV_N + g * 8);

    const int prow = (wave * 16 + l16) * 16;
    const int kg_swz = (g ^ (kq & 7)) * 8;   // (kq+32)&7 == kq&7

    for (int t = 0; t < SEQ / 64; t++) {
        const int cur = t & 1;
        *reinterpret_cast<bf16x8*>(&sK[cur][kq * 64 + kg_swz])        = kreg[0];
        *reinterpret_cast<bf16x8*>(&sK[cur][(kq + 32) * 64 + kg_swz]) = kreg[1];
        // sigma(g) = 4g ^ 16*(g&1): toggles bank-bit4 on odd d-groups so PV
        // reads span all 32 banks; writes stay 2 lanes/bank (free).
        const int pwv = kp ^ (4 * g) ^ ((g & 1) << 4);
        {
            // pack V[2kp][d] (low16) | V[2kp+1][d] (high16), one v_perm_b32 each
            const u32* v0w = reinterpret_cast<const u32*>(&vreg[0]);
            const u32* v1w = reinterpret_cast<const u32*>(&vreg[1]);
            #pragma unroll
            for (int e = 0; e < 8; e++) {
                const u32 pack = __builtin_amdgcn_perm(
                    v1w[e >> 1], v0w[e >> 1],
                    (e & 1) ? 0x07060302u : 0x05040100u);
                sVt32[cur][(g * 8 + e) * 32 + pwv] = pack;
            }
        }
        if (t + 1 < SEQ / 64) {
            const size_t base = (size_t)(t + 1) * 64;
            kreg[0] = *reinterpret_cast<const bf16x8*>(Kg + (base + kq)      * QKV_N + g * 8);
            kreg[1] = *reinterpret_cast<const bf16x8*>(Kg + (base + kq + 32) * QKV_N + g * 8);
            vreg[0] = *reinterpret_cast<const bf16x8*>(Vg + (base + 2 * kp)     * QKV_N + g * 8);
            vreg[1] = *reinterpret_cast<const bf16x8*>(Vg + (base + 2 * kp + 1) * QKV_N + g * 8);
        }
        __syncthreads();

        // S^T = K Qs^T: rows = keys (kt*16 + quad*4 + r), cols = q (l16)
        f32x4 s[4];
        __builtin_amdgcn_s_setprio(1);
        #pragma unroll
        for (int kt = 0; kt < 4; kt++) {
            const int krow = kt * 16 + l16;
            const int ks   = krow & 7;
            bf16x8 kf0 = *reinterpret_cast<const bf16x8*>(
                &sK[cur][krow * 64 + ((quad ^ ks) * 8)]);
            bf16x8 kf1 = *reinterpret_cast<const bf16x8*>(
                &sK[cur][krow * 64 + (((quad + 4) ^ ks) * 8)]);
            f32x4 a = {};
            a = __builtin_amdgcn_mfma_f32_16x16x32_bf16(kf0, qf[0], a, 0, 0, 0);
            a = __builtin_amdgcn_mfma_f32_16x16x32_bf16(kf1, qf[1], a, 0, 0, 0);
            s[kt] = a;
        }
        __builtin_amdgcn_s_setprio(0);

        // P = exp2(S), split into halves to overlap TRANS with LDS latency.
        union { struct { u32x2 lo, hi; } s2; bf16x8 v; } pu0, pu1;

        // half 0: keys 0..31 (kt = 0,1)
        #pragma unroll
        for (int kt = 0; kt < 2; kt++) {
            float p0 = EXP2(s[kt][0]);
            float p1 = EXP2(s[kt][1]);
            float p2 = EXP2(s[kt][2]);
            float p3 = EXP2(s[kt][3]);
            l_acc += p0; l_acc += p1; l_acc += p2; l_acc += p3;
            u32x2 pk;
            pk.x = cvt_pk_bf16(p0, p1);
            pk.y = cvt_pk_bf16(p2, p3);
            sP2[prow + ((kt * 4 + quad) ^ l16)] = pk;   // keys kt*16+quad*4..+3
        }
        // issue pu0 reads; latency hidden by half-1 exp/pack below
        pu0.s2.lo = sP2[prow + ((2 * quad)     ^ l16)];   // keys quad*8..+3
        pu0.s2.hi = sP2[prow + ((2 * quad + 1) ^ l16)];   // keys quad*8+4..+7

        // half 1: keys 32..63 (kt = 2,3)
        #pragma unroll
        for (int kt = 2; kt < 4; kt++) {
            float p0 = EXP2(s[kt][0]);
            float p1 = EXP2(s[kt][1]);
            float p2 = EXP2(s[kt][2]);
            float p3 = EXP2(s[kt][3]);
            l_acc += p0; l_acc += p1; l_acc += p2; l_acc += p3;
            u32x2 pk;
            pk.x = cvt_pk_bf16(p0, p1);
            pk.y = cvt_pk_bf16(p2, p3);
            sP2[prow + ((kt * 4 + quad) ^ l16)] = pk;
        }
        pu1.s2.lo = sP2[prow + ((8 + 2 * quad) ^ l16)];   // keys 32+quad*8..+3
        pu1.s2.hi = sP2[prow + ((9 + 2 * quad) ^ l16)];   // keys 32+quad*8+4..+7

        // O^T += V^T P^T; half0 MFMAs overlap pu1 read latency.
        __builtin_amdgcn_s_setprio(1);
        #pragma unroll
        for (int dt = 0; dt < 4; dt++) {
            const int row = dt * 16 + l16;
            const int hr  = (row >> 3) & 7;
            const int sw  = (4 * hr) ^ ((hr & 1) << 4);
            bf16x8 vf0 = *reinterpret_cast<const bf16x8*>(
                &sVt32[cur][row * 32 + ((quad * 4) ^ sw)]);
            O[dt] = __builtin_amdgcn_mfma_f32_16x16x32_bf16(vf0, pu0.v, O[dt], 0, 0, 0);
        }
        #pragma unroll
        for (int dt = 0; dt < 4; dt++) {
            const int row = dt * 16 + l16;
            const int hr  = (row >> 3) & 7;
            const int sw  = (4 * hr) ^ ((hr & 1) << 4);
            bf16x8 vf1 = *reinterpret_cast<const bf16x8*>(
                &sVt32[cur][row * 32 + ((16 + quad * 4) ^ sw)]);
            O[dt] = __builtin_amdgcn_mfma_f32_16x16x32_bf16(vf1, pu1.v, O[dt], 0, 0, 0);
        }
        __builtin_amdgcn_s_setprio(0);
    }

    // epilogue: reduce l over quads, write O^T/l to q slot
    float lv = l_acc;
    lv += __shfl_xor(lv, 16, 64);
    lv += __shfl_xor(lv, 32, 64);
    const float inv = 1.0f / lv;
    const int qrow = qt * 64 + wave * 16 + l16;
    u16* orow = qkvb + bb + (size_t)qrow * QKV_N + h * DHEAD;
    #pragma unroll
    for (int dt = 0; dt < 4; dt++) {
        u32x2 pk;
        pk.x = cvt_pk_bf16(O[dt][0] * inv, O[dt][1] * inv);
        pk.y = cvt_pk_bf16(O[dt][2] * inv, O[dt][3] * inv);
        *reinterpret_cast<u32x2*>(&orow[dt * 16 + quad * 4]) = pk;
    }
}

// ---------------------------------------------------------------------------
extern "C" void kernel_launch(void* const* d_in, const int* in_sizes, int n_in,
                              void* d_out, int out_size, void* d_ws, size_t ws_size,
                              hipStream_t stream)
{
    const float* x      = (const float*)d_in[0];
    const float* cosb   = (const float*)d_in[1];
    const float* sinb   = (const float*)d_in[2];
    const float* qkv_w  = (const float*)d_in[3];
    const float* qkv_b  = (const float*)d_in[4];
    const float* proj_w = (const float*)d_in[5];
    const float* proj_b = (const float*)d_in[6];
    const float* qn_w   = (const float*)d_in[7];
    const float* kn_w   = (const float*)d_in[8];
    float* out = (float*)d_out;

    char* ws = (char*)d_ws;
    u16* qkvb = (u16*)(ws);                    // 4096 x 2304 bf16 = 18,874,368 B
    u16* xb   = (u16*)(ws + 18874368);         // 4096 x 768  bf16 =  6,291,456 B
    u16* wT   = (u16*)(ws + 25165824);         // 2304 x 768  bf16 =  3,538,944 B
    u16* pwT  = (u16*)(ws + 28704768);         //  768 x 768  bf16 =  1,179,648 B

    // 0. fused prep: x->bf16, both weight transposes
    prep_kernel<<<PREP_CONV + PREP_TQ + PREP_TP, 256, 0, stream>>>(
        x, xb, qkv_w, wT, proj_w, pwT);

    // 1. QKV projection + fused RMSNorm/RoPE -> bf16 qkv buffer (dbuf)
    gemm_qkv_mfma_kernel<<<576, 256, 0, stream>>>(
        xb, CDIM, wT, qkv_b, cosb, sinb, qn_w, kn_w, qkvb, QKV_N, CDIM);

    // 2. Flash MFMA attention (out -> q slot of qkvb)
    attn_mfma_kernel<<<dim3(SEQ / 64, HEADS, BATCH), 256, 0, stream>>>(qkvb);

    // 3. Output projection (bf16 MFMA 64x64 dbuf, fp32 out)
    gemm_proj_mfma_kernel<<<768, 256, 0, stream>>>(
        qkvb, QKV_N, pwT, proj_b, out, CDIM, CDIM);
}